// Round 10
// baseline (194.855 us; speedup 1.0000x reference)
//
#include <hip/hip_runtime.h>

#define NB 32
#define CCH 128
#define HH 56
#define WWD 56
#define HWP (HH*WWD)   // 3136
#define K3C (3*CCH)    // 384
#define SPLITK 8

typedef _Float16 half8 __attribute__((ext_vector_type(8)));
typedef float floatx4 __attribute__((ext_vector_type(4)));

// ---------------- fused prep: blocks [0,3136) do x->xh,xT; blocks [3136,3520) do p2w cvt ------
// block 3136 additionally zeroes the 1KB zbuf (gemm2 OOB-row source for global_load_lds).
__global__ __launch_bounds__(256) void prep_kernel(const float* __restrict__ x,
                                                   const float* __restrict__ p2w,
                                                   _Float16* __restrict__ xh,
                                                   _Float16* __restrict__ xT,
                                                   _Float16* __restrict__ p2wh,
                                                   float* __restrict__ zbuf) {
    __shared__ _Float16 t[64 * 72];
    const int bid = blockIdx.x;
    const int tid = threadIdx.x;

    if (bid >= 3136) {
        if (bid == 3136) zbuf[tid] = 0.f;    // 1KB zero scratch (re-zeroed every iteration)
        const int row = bid - 3136;          // k' = j*128 + c
        const int j = row >> 7;
        const int c = row & 127;
        const float* s = p2w + ((size_t)c * 3 + j) * HWP;
        _Float16* d = p2wh + (size_t)row * HWP;
        for (int base = tid * 8; base < HWP; base += 2048) {
            const float4 a = *(const float4*)(s + base);
            const float4 b = *(const float4*)(s + base + 4);
            half8 v;
            v[0] = (_Float16)a.x; v[1] = (_Float16)a.y; v[2] = (_Float16)a.z; v[3] = (_Float16)a.w;
            v[4] = (_Float16)b.x; v[5] = (_Float16)b.y; v[6] = (_Float16)b.z; v[7] = (_Float16)b.w;
            *(half8*)(d + base) = v;
        }
        return;
    }

    const int r8  = bid & 7;
    const int g   = bid >> 3;            // 0..391
    const int n   = r8 + 8 * (g / 98);
    const int rem = g % 98;
    const int c0  = (rem / 49) * 64;
    const int p0  = (rem % 49) * 64;
    const int r   = tid >> 2;            // 0..63
    const int seg = (tid & 3) * 16;

    const float* src = x + ((size_t)n * CCH + c0 + r) * HWP + p0 + seg;
    const float4 a0 = *(const float4*)(src);
    const float4 a1 = *(const float4*)(src + 4);
    const float4 a2 = *(const float4*)(src + 8);
    const float4 a3 = *(const float4*)(src + 12);
    half8 v0, v1;
    v0[0] = (_Float16)a0.x; v0[1] = (_Float16)a0.y; v0[2] = (_Float16)a0.z; v0[3] = (_Float16)a0.w;
    v0[4] = (_Float16)a1.x; v0[5] = (_Float16)a1.y; v0[6] = (_Float16)a1.z; v0[7] = (_Float16)a1.w;
    v1[0] = (_Float16)a2.x; v1[1] = (_Float16)a2.y; v1[2] = (_Float16)a2.z; v1[3] = (_Float16)a2.w;
    v1[4] = (_Float16)a3.x; v1[5] = (_Float16)a3.y; v1[6] = (_Float16)a3.z; v1[7] = (_Float16)a3.w;

    _Float16* dxh = xh + ((size_t)n * CCH + c0 + r) * HWP + p0 + seg;
    *(half8*)(dxh)     = v0;
    *(half8*)(dxh + 8) = v1;
    *(half8*)(&t[r * 72 + seg])     = v0;
    *(half8*)(&t[r * 72 + seg + 8]) = v1;
    __syncthreads();
    _Float16* dst = xT + ((size_t)n * HWP + p0 + r) * CCH + c0 + seg;
    half8 w0, w1;
#pragma unroll
    for (int i = 0; i < 8; ++i) w0[i] = t[(seg + i) * 72 + r];
#pragma unroll
    for (int i = 0; i < 8; ++i) w1[i] = t[(seg + 8 + i) * 72 + r];
    *(half8*)(dst) = w0;
    *(half8*)(dst + 8) = w1;
}

// ---------------- GEMM1 (r4 config: split-K, 128x128, grid 768, 1-deep reg-staging) -----------
// Staging is VALU-fused (A = p2w*x, B = x+roll(x)) so global_load_lds does NOT apply here.
// 2-deep regressed (r5, VGPR cliff); Tn=64 neutral (r9). This shape is the best measured.
__global__ __launch_bounds__(256) void gemm1_kernel(const _Float16* __restrict__ xh,
                                                    const _Float16* __restrict__ p2wh,
                                                    _Float16* __restrict__ part) {
    __shared__ _Float16 As[128 * 72];
    __shared__ _Float16 Bs[128 * 72];

    const int bid   = blockIdx.x;
    const int r8    = bid & 7;
    const int g     = bid >> 3;
    const int n     = r8 + 8 * (g / 24);
    const int inner = g % 24;
    const int jb    = inner % 3;            // uniform j for this block
    const int m0    = jb * 128;
    const int s     = inner / 3;
    const int i0    = (s * 49) >> 3;
    const int i1    = ((s + 1) * 49) >> 3;

    const int tid  = threadIdx.x;
    const int lrow = tid >> 3;              // 0..31
    const int lcol = (tid & 7) * 8;         // 0..56

    const int ashift = 112 * (jb - 1);
    const _Float16* xh_n = xh + (size_t)n * CCH * HWP;
    const _Float16* pw_m = p2wh + (size_t)m0 * HWP;

    const int wave = tid >> 6;
    const int lane = tid & 63;
    const int l15  = lane & 15;
    const int quad = lane >> 4;
    const int wm   = (wave >> 1) * 64;
    const int wn   = (wave & 1) * 64;

    floatx4 acc[4][4];
#pragma unroll
    for (int a = 0; a < 4; ++a)
#pragma unroll
        for (int b = 0; b < 4; ++b) acc[a][b] = (floatx4){0.f,0.f,0.f,0.f};

    half8 xv[4], wv[4], uv[4], vv[4];   // in-flight staging registers

    // ---- prologue: issue loads for it = i0 ----
    {
        const int p0 = i0 * 64;
        const int pA = p0 + lcol;
        const int srcp  = pA + ashift;
        const int proll = (pA >= WWD) ? (pA - WWD) : (pA + (HH - 1) * WWD);
        const bool ok = (srcp >= 0 && srcp < HWP);
#pragma unroll
        for (int sg = 0; sg < 4; ++sg) {
            const int row = sg * 32 + lrow;
            const _Float16* xaS = xh_n + (size_t)row * HWP;
            if (ok) xv[sg] = *(const half8*)(xaS + srcp);
            else { half8 z; for (int i = 0; i < 8; ++i) z[i] = (_Float16)0.f; xv[sg] = z; }
            wv[sg] = *(const half8*)(pw_m + (size_t)row * HWP + pA);
            uv[sg] = *(const half8*)(xaS + pA);
            vv[sg] = *(const half8*)(xaS + proll);
        }
    }

    for (int it = i0; it < i1; ++it) {
#pragma unroll
        for (int sg = 0; sg < 4; ++sg) {
            const int row = sg * 32 + lrow;
            *(half8*)(&As[row * 72 + lcol]) = xv[sg] * wv[sg];  // t2' = p2w' * x(shifted)
            *(half8*)(&Bs[row * 72 + lcol]) = uv[sg] + vv[sg];  // t6 = x + roll(x)
        }
        __syncthreads();
        if (it + 1 < i1) {
            const int p0 = (it + 1) * 64;
            const int pA = p0 + lcol;
            const int srcp  = pA + ashift;
            const int proll = (pA >= WWD) ? (pA - WWD) : (pA + (HH - 1) * WWD);
            const bool ok = (srcp >= 0 && srcp < HWP);
#pragma unroll
            for (int sg = 0; sg < 4; ++sg) {
                const int row = sg * 32 + lrow;
                const _Float16* xaS = xh_n + (size_t)row * HWP;
                if (ok) xv[sg] = *(const half8*)(xaS + srcp);
                else { half8 z; for (int i = 0; i < 8; ++i) z[i] = (_Float16)0.f; xv[sg] = z; }
                wv[sg] = *(const half8*)(pw_m + (size_t)row * HWP + pA);
                uv[sg] = *(const half8*)(xaS + pA);
                vv[sg] = *(const half8*)(xaS + proll);
            }
        }
#pragma unroll
        for (int ks = 0; ks < 2; ++ks) {
            const int ko = ks * 32 + quad * 8;
            half8 af[4], bf[4];
#pragma unroll
            for (int mi = 0; mi < 4; ++mi) af[mi] = *(half8*)(&As[(wm + mi * 16 + l15) * 72 + ko]);
#pragma unroll
            for (int ni = 0; ni < 4; ++ni) bf[ni] = *(half8*)(&Bs[(wn + ni * 16 + l15) * 72 + ko]);
#pragma unroll
            for (int mi = 0; mi < 4; ++mi)
#pragma unroll
                for (int ni = 0; ni < 4; ++ni)
                    acc[mi][ni] = __builtin_amdgcn_mfma_f32_16x16x32_f16(af[mi], bf[ni], acc[mi][ni], 0, 0, 0);
        }
        __syncthreads();
    }

    _Float16* pbase = part + (size_t)(s * NB + n) * K3C * CCH;
#pragma unroll
    for (int mi = 0; mi < 4; ++mi)
#pragma unroll
        for (int ni = 0; ni < 4; ++ni) {
            const int kr = m0 + wm + mi * 16 + quad * 4;
            const int cc = wn + ni * 16 + l15;
#pragma unroll
            for (int r2 = 0; r2 < 4; ++r2)
                pbase[(size_t)(kr + r2) * CCH + cc] = (_Float16)acc[mi][ni][r2];
        }
}

// ---------------- reduce: t7T[n][c2][k'] = (1/56) * sum_s part[s][n][k'][c2] ----------------
__global__ __launch_bounds__(256) void reduce_kernel(const _Float16* __restrict__ part,
                                                     _Float16* __restrict__ t7T) {
    __shared__ _Float16 tile[16][130];
    const int n  = blockIdx.y;
    const int k0 = blockIdx.x * 16;
    const int t  = threadIdx.x;
    const int c2 = t & 127;
    const int kh = t >> 7;
#pragma unroll
    for (int kk = 0; kk < 8; ++kk) {
        const int k = kh * 8 + kk;
        float sum = 0.f;
#pragma unroll
        for (int sp = 0; sp < SPLITK; ++sp)
            sum += (float)part[(((size_t)sp * NB + n) * K3C + k0 + k) * CCH + c2];
        tile[k][c2] = (_Float16)(sum * (1.0f / 56.0f));
    }
    __syncthreads();
    const int kt = t & 15;
    const int c0 = t >> 4;
#pragma unroll
    for (int cc = 0; cc < 8; ++cc) {
        const int cw = c0 * 8 + cc;
        t7T[((size_t)n * CCH + cw) * K3C + k0 + kt] = tile[kt][cw];
    }
}

// ---------------- GEMM2 (global_load_lds staging + pre-swizzled source, fused t8) -------------
// Staging is two PURE COPIES (t7T rows -> As, xT rows -> Bs) so global_load_lds applies:
// no staging VGPRs, no VALU round-trip, LDS unpadded.  T2/rule-21: LDS is linear [row][64];
// the bank swizzle is applied on BOTH sides as the involution chunk^=(row&7):
//   source: lane (lane&7) fetches global chunk (lane&7)^(lane>>3)   [row&7 == lane>>3]
//   read:   fragment chunk ch read at LDS chunk ch^(row&7)  -> 2 lanes/bank (free, m136)
// OOB B-rows point their per-lane source at zbuf (1KB zeros, re-zeroed by prep).
__global__ __launch_bounds__(256) void gemm2_kernel(const _Float16* __restrict__ xh,
                                                    const _Float16* __restrict__ xT,
                                                    const _Float16* __restrict__ t7T,
                                                    const float* __restrict__ conv_w,
                                                    const float* __restrict__ p5w,
                                                    const _Float16* __restrict__ zbuf,
                                                    float* __restrict__ out) {
    // lds map (f16 units): As [0,8192) = [128][64] swz | Bs [8704,12800) = [64][64] swz
    // phase-0 scratch overlays [0,8704) as [64 rows][136 stride]
    __shared__ _Float16 lds[12800];
    __shared__ float t8tile[4 * 64];    // [o][p_local]
    __shared__ float wf[4 * 128];       // conv_w * p5w
    _Float16* As = lds;
    _Float16* Bs = lds + 8704;

    const int bid = blockIdx.x;
    const int r8  = bid & 7;
    const int g   = bid >> 3;
    const int n   = r8 + 8 * (g / 49);
    const int pt0 = (g % 49) * 64;
    const int tid = threadIdx.x;

    const int wave = tid >> 6;
    const int lane = tid & 63;
    const int l15  = lane & 15;
    const int quad = lane >> 4;
    const int wm   = (wave >> 1) * 64;
    const int wn   = (wave & 1) * 32;

    const int lr  = lane >> 3;            // row-in-8-group
    const int gcs = (lane & 7) ^ lr;      // pre-swizzled source chunk

    const _Float16* t7n = t7T + (size_t)n * CCH * K3C;
    const _Float16* xTn = xT + (size_t)n * HWP * CCH;

    // B staging row geometry (fixed across k-steps): prow = pt0 + (wave*2+cc)*8 + lr
    int hbB[2], wbB[2];
#pragma unroll
    for (int cc = 0; cc < 2; ++cc) {
        const int prow = pt0 + (wave * 2 + cc) * 8 + lr;
        hbB[cc] = prow / WWD;
        wbB[cc] = prow - hbB[cc] * WWD;
    }

    floatx4 acc[4][2];
#pragma unroll
    for (int a = 0; a < 4; ++a)
#pragma unroll
        for (int b = 0; b < 2; ++b) acc[a][b] = (floatx4){0.f,0.f,0.f,0.f};

    // ---- phase 0: compute t8tile (scratch overlays As region; stride 136) ----
    {
        wf[tid]       = conv_w[tid] * p5w[tid & 127];
        wf[tid + 256] = conv_w[tid + 256] * p5w[tid & 127];
        _Float16* tr = lds;
        const int coff = (tid & 15) * 8;          // 0..120
#pragma unroll
        for (int q = 0; q < 4; ++q) {
            const int row = q * 16 + (tid >> 4);  // 0..63
            const int p   = pt0 + row;
            const int srcrow = (p >= WWD) ? (p - WWD) : (p + (HH - 1) * WWD);
            *(half8*)(&tr[row * 136 + coff]) = *(const half8*)(xTn + (size_t)srcrow * CCH + coff);
        }
        __syncthreads();
        const int o  = tid >> 6;                  // wave-uniform
        const int pl = tid & 63;
        const float* wrow = wf + o * 128;
        float a = 0.f;
#pragma unroll
        for (int cs = 0; cs < 16; ++cs) {
            const half8 v = *(const half8*)(&tr[pl * 136 + cs * 8]);
#pragma unroll
            for (int i = 0; i < 8; ++i) a += wrow[cs * 8 + i] * (float)v[i];
        }
        t8tile[o * 64 + pl] = a;
        __syncthreads();   // scratch free; t8tile visible
    }

    // ---- main loop: 1-deep global_load_lds staging (m97 structure) ----
    for (int i = 0; i < 6; ++i) {
        const int kn  = i * 64;
        const int jn  = i >> 1;
        const int c0k = (i & 1) * 64;
        // A: 4 calls/thread, each wave-instr stages 8 rows x 128B, linear LDS dest
#pragma unroll
        for (int cc = 0; cc < 4; ++cc) {
            const int rowA = (wave * 4 + cc) * 8 + lr;
            const _Float16* srcA = t7n + (size_t)rowA * K3C + kn + gcs * 8;
            __builtin_amdgcn_global_load_lds(
                (const __attribute__((address_space(1))) void*)srcA,
                (__attribute__((address_space(3))) void*)(As + (wave * 4 + cc) * 512),
                16, 0, 0);
        }
        // B: 2 calls/thread; OOB rows read zbuf zeros
#pragma unroll
        for (int cc = 0; cc < 2; ++cc) {
            const int wsrc = wbB[cc] + 2 * jn - 2;
            const _Float16* srcB = (wsrc >= 0 && wsrc < WWD)
                ? xTn + ((size_t)hbB[cc] * WWD + wsrc) * CCH + c0k + gcs * 8
                : zbuf + lane * 8;
            __builtin_amdgcn_global_load_lds(
                (const __attribute__((address_space(1))) void*)srcB,
                (__attribute__((address_space(3))) void*)(Bs + (wave * 2 + cc) * 512),
                16, 0, 0);
        }
        __syncthreads();   // barrier drains vmcnt -> tiles ready
        // ---- MFMA (swizzled fragment reads: chunk = (ks*4+quad) ^ (l15&7)) ----
#pragma unroll
        for (int ks = 0; ks < 2; ++ks) {
            const int ch = ks * 4 + quad;
            const int sw = (ch ^ (l15 & 7)) * 8;
            half8 af[4], bf[2];
#pragma unroll
            for (int mi = 0; mi < 4; ++mi)
                af[mi] = *(half8*)(&As[(wm + mi * 16 + l15) * 64 + sw]);
#pragma unroll
            for (int ni = 0; ni < 2; ++ni)
                bf[ni] = *(half8*)(&Bs[(wn + ni * 16 + l15) * 64 + sw]);
#pragma unroll
            for (int mi = 0; mi < 4; ++mi)
#pragma unroll
                for (int ni = 0; ni < 2; ++ni)
                    acc[mi][ni] = __builtin_amdgcn_mfma_f32_16x16x32_f16(af[mi], bf[ni], acc[mi][ni], 0, 0, 0);
        }
        __syncthreads();
    }

    const float sc = 0.05103103630798288f;  // 1/sqrt(384)
#pragma unroll
    for (int mi = 0; mi < 4; ++mi)
#pragma unroll
        for (int ni = 0; ni < 2; ++ni) {
            const int ccb = wm + mi * 16 + quad * 4;
            const int lp  = wn + ni * 16 + l15;     // p_local in [0,64)
            const int pp  = pt0 + lp;
#pragma unroll
            for (int r2 = 0; r2 < 4; ++r2) {
                const int c2 = ccb + r2;            // o = c2 & 3 == r2 (wave-uniform)
                const size_t oidx = ((size_t)n * CCH + c2) * HWP + pp;
                const float t9 = t8tile[r2 * 64 + lp] * (float)xh[oidx];
                out[oidx] = acc[mi][ni][r2] * sc + t9;
            }
        }
}

extern "C" void kernel_launch(void* const* d_in, const int* in_sizes, int n_in,
                              void* d_out, int out_size, void* d_ws, size_t ws_size,
                              hipStream_t stream) {
    const float* x      = (const float*)d_in[0];
    const float* p2w    = (const float*)d_in[1];
    const float* p5w    = (const float*)d_in[2];
    const float* conv_w = (const float*)d_in[3];
    float* out = (float*)d_out;

    // ws: xh 25.69MB | p2wh 2.41MB | zbuf 1KB (in ex-t8 hole) | t7T 3.15MB | xT 25.69MB
    char* ws = (char*)d_ws;
    _Float16* xh   = (_Float16*)ws;
    _Float16* p2wh = (_Float16*)(ws + 25690112);
    float*    zb   = (float*)   (ws + 25690112 + 2408448);
    _Float16* t7T  = (_Float16*)(ws + 25690112 + 2408448 + 1605632);
    _Float16* xT   = (_Float16*)(ws + 25690112 + 2408448 + 1605632 + 3145728);
    _Float16* part = (_Float16*)out;  // f16 partials [s][n][k'][c2] (25.2MB), consumed before gemm2

    prep_kernel<<<dim3(3520), dim3(256), 0, stream>>>(x, p2w, xh, xT, p2wh, zb);
    gemm1_kernel<<<dim3(768), dim3(256), 0, stream>>>(xh, p2wh, part);
    reduce_kernel<<<dim3(24, NB), dim3(256), 0, stream>>>(part, t7T);
    gemm2_kernel<<<dim3(1568), dim3(256), 0, stream>>>(xh, xT, t7T, conv_w, p5w,
                                                       (const _Float16*)zb, out);
}

// Round 11
// 178.823 us; speedup vs baseline: 1.0897x; 1.0897x over previous
//
#include <hip/hip_runtime.h>

#define NB 32
#define CCH 128
#define HH 56
#define WWD 56
#define HWP (HH*WWD)   // 3136
#define K3C (3*CCH)    // 384
#define SPLITK 8

typedef _Float16 half8 __attribute__((ext_vector_type(8)));
typedef float floatx4 __attribute__((ext_vector_type(4)));

// ---------------- prep: p2w f32 -> f16, K-permuted: row k' = j*128+c <- src row (c,j) ----------
__global__ __launch_bounds__(256) void cvtp2w_kernel(const float* __restrict__ src,
                                                     _Float16* __restrict__ dst) {
    const int row = blockIdx.x;          // k' = j*128 + c
    const int j = row >> 7;
    const int c = row & 127;
    const float* s = src + ((size_t)c * 3 + j) * HWP;
    _Float16* d = dst + (size_t)row * HWP;
    for (int base = threadIdx.x * 8; base < HWP; base += 2048) {
        const float4 a = *(const float4*)(s + base);
        const float4 b = *(const float4*)(s + base + 4);
        half8 v;
        v[0] = (_Float16)a.x; v[1] = (_Float16)a.y; v[2] = (_Float16)a.z; v[3] = (_Float16)a.w;
        v[4] = (_Float16)b.x; v[5] = (_Float16)b.y; v[6] = (_Float16)b.z; v[7] = (_Float16)b.w;
        *(half8*)(d + base) = v;
    }
}

// ---------------- fused: x f32 -> xh f16 AND xT[n][p][c] transpose (64x64 LDS tiles) ----------
// grid 3136 = 8 * (4n * 2c * 49p); XCD swizzle n%8 == bid%8
__global__ __launch_bounds__(256) void cvt_xt_kernel(const float* __restrict__ x,
                                                     _Float16* __restrict__ xh,
                                                     _Float16* __restrict__ xT) {
    __shared__ _Float16 t[64 * 72];
    const int bid = blockIdx.x;
    const int r8  = bid & 7;
    const int g   = bid >> 3;            // 0..391
    const int n   = r8 + 8 * (g / 98);
    const int rem = g % 98;
    const int c0  = (rem / 49) * 64;
    const int p0  = (rem % 49) * 64;
    const int tid = threadIdx.x;
    const int r   = tid >> 2;            // 0..63
    const int seg = (tid & 3) * 16;

    const float* src = x + ((size_t)n * CCH + c0 + r) * HWP + p0 + seg;
    const float4 a0 = *(const float4*)(src);
    const float4 a1 = *(const float4*)(src + 4);
    const float4 a2 = *(const float4*)(src + 8);
    const float4 a3 = *(const float4*)(src + 12);
    half8 v0, v1;
    v0[0] = (_Float16)a0.x; v0[1] = (_Float16)a0.y; v0[2] = (_Float16)a0.z; v0[3] = (_Float16)a0.w;
    v0[4] = (_Float16)a1.x; v0[5] = (_Float16)a1.y; v0[6] = (_Float16)a1.z; v0[7] = (_Float16)a1.w;
    v1[0] = (_Float16)a2.x; v1[1] = (_Float16)a2.y; v1[2] = (_Float16)a2.z; v1[3] = (_Float16)a2.w;
    v1[4] = (_Float16)a3.x; v1[5] = (_Float16)a3.y; v1[6] = (_Float16)a3.z; v1[7] = (_Float16)a3.w;

    _Float16* dxh = xh + ((size_t)n * CCH + c0 + r) * HWP + p0 + seg;
    *(half8*)(dxh)     = v0;
    *(half8*)(dxh + 8) = v1;
    *(half8*)(&t[r * 72 + seg])     = v0;
    *(half8*)(&t[r * 72 + seg + 8]) = v1;
    __syncthreads();
    // write rows of xT: p_local = r, c chunk = seg..seg+15
    _Float16* dst = xT + ((size_t)n * HWP + p0 + r) * CCH + c0 + seg;
    half8 w0, w1;
#pragma unroll
    for (int i = 0; i < 8; ++i) w0[i] = t[(seg + i) * 72 + r];
#pragma unroll
    for (int i = 0; i < 8; ++i) w1[i] = t[(seg + 8 + i) * 72 + r];
    *(half8*)(dst) = w0;
    *(half8*)(dst + 8) = w1;
}

// ---------------- GEMM1 (split-K, permuted K, f16 partials, coalesced staging) ----------
// k' = j*128+c; m0-block has uniform j. Tm=128, Tn=128, BK=64; grid 768; swizzle n%8==bid%8.
// Staging map: row = s*32 + (tid>>3), col = (tid&7)*8 -> each wave-instr reads 8 rows x 128B.
__global__ __launch_bounds__(256) void gemm1_kernel(const _Float16* __restrict__ xh,
                                                    const _Float16* __restrict__ p2wh,
                                                    _Float16* __restrict__ part) {
    __shared__ _Float16 As[128 * 72];
    __shared__ _Float16 Bs[128 * 72];

    const int bid   = blockIdx.x;
    const int r8    = bid & 7;
    const int g     = bid >> 3;
    const int n     = r8 + 8 * (g / 24);
    const int inner = g % 24;
    const int jb    = inner % 3;            // uniform j for this block
    const int m0    = jb * 128;
    const int s     = inner / 3;
    const int i0    = (s * 49) >> 3;
    const int i1    = ((s + 1) * 49) >> 3;

    const int tid  = threadIdx.x;
    const int lrow = tid >> 3;              // 0..31
    const int lcol = (tid & 7) * 8;         // 0..56

    const int ashift = 112 * (jb - 1);
    const _Float16* xh_n = xh + (size_t)n * CCH * HWP;
    const _Float16* pw_m = p2wh + (size_t)m0 * HWP;

    const int wave = tid >> 6;
    const int lane = tid & 63;
    const int l15  = lane & 15;
    const int quad = lane >> 4;
    const int wm   = (wave >> 1) * 64;
    const int wn   = (wave & 1) * 64;

    floatx4 acc[4][4];
#pragma unroll
    for (int a = 0; a < 4; ++a)
#pragma unroll
        for (int b = 0; b < 4; ++b) acc[a][b] = (floatx4){0.f,0.f,0.f,0.f};

    half8 xv[4], wv[4], uv[4], vv[4];   // in-flight staging registers

    // ---- prologue: issue loads for it = i0 ----
    {
        const int p0 = i0 * 64;
        const int pA = p0 + lcol;
        const int srcp  = pA + ashift;
        const int proll = (pA >= WWD) ? (pA - WWD) : (pA + (HH - 1) * WWD);
        const bool ok = (srcp >= 0 && srcp < HWP);
#pragma unroll
        for (int sg = 0; sg < 4; ++sg) {
            const int row = sg * 32 + lrow;
            const _Float16* xaS = xh_n + (size_t)row * HWP;
            if (ok) xv[sg] = *(const half8*)(xaS + srcp);
            else { half8 z; for (int i = 0; i < 8; ++i) z[i] = (_Float16)0.f; xv[sg] = z; }
            wv[sg] = *(const half8*)(pw_m + (size_t)row * HWP + pA);
            uv[sg] = *(const half8*)(xaS + pA);
            vv[sg] = *(const half8*)(xaS + proll);
        }
    }

    for (int it = i0; it < i1; ++it) {
        // ---- commit staging regs to LDS ----
#pragma unroll
        for (int sg = 0; sg < 4; ++sg) {
            const int row = sg * 32 + lrow;
            *(half8*)(&As[row * 72 + lcol]) = xv[sg] * wv[sg];  // t2' = p2w' * x(shifted)
            *(half8*)(&Bs[row * 72 + lcol]) = uv[sg] + vv[sg];  // t6 = x + roll(x)
        }
        __syncthreads();
        // ---- issue next iteration's loads (overlap with MFMA) ----
        if (it + 1 < i1) {
            const int p0 = (it + 1) * 64;
            const int pA = p0 + lcol;
            const int srcp  = pA + ashift;
            const int proll = (pA >= WWD) ? (pA - WWD) : (pA + (HH - 1) * WWD);
            const bool ok = (srcp >= 0 && srcp < HWP);
#pragma unroll
            for (int sg = 0; sg < 4; ++sg) {
                const int row = sg * 32 + lrow;
                const _Float16* xaS = xh_n + (size_t)row * HWP;
                if (ok) xv[sg] = *(const half8*)(xaS + srcp);
                else { half8 z; for (int i = 0; i < 8; ++i) z[i] = (_Float16)0.f; xv[sg] = z; }
                wv[sg] = *(const half8*)(pw_m + (size_t)row * HWP + pA);
                uv[sg] = *(const half8*)(xaS + pA);
                vv[sg] = *(const half8*)(xaS + proll);
            }
        }
        // ---- MFMA on current LDS tile ----
#pragma unroll
        for (int ks = 0; ks < 2; ++ks) {
            const int ko = ks * 32 + quad * 8;
            half8 af[4], bf[4];
#pragma unroll
            for (int mi = 0; mi < 4; ++mi) af[mi] = *(half8*)(&As[(wm + mi * 16 + l15) * 72 + ko]);
#pragma unroll
            for (int ni = 0; ni < 4; ++ni) bf[ni] = *(half8*)(&Bs[(wn + ni * 16 + l15) * 72 + ko]);
#pragma unroll
            for (int mi = 0; mi < 4; ++mi)
#pragma unroll
                for (int ni = 0; ni < 4; ++ni)
                    acc[mi][ni] = __builtin_amdgcn_mfma_f32_16x16x32_f16(af[mi], bf[ni], acc[mi][ni], 0, 0, 0);
        }
        __syncthreads();
    }

    _Float16* pbase = part + (size_t)(s * NB + n) * K3C * CCH;
#pragma unroll
    for (int mi = 0; mi < 4; ++mi)
#pragma unroll
        for (int ni = 0; ni < 4; ++ni) {
            const int kr = m0 + wm + mi * 16 + quad * 4;
            const int cc = wn + ni * 16 + l15;
#pragma unroll
            for (int r2 = 0; r2 < 4; ++r2)
                pbase[(size_t)(kr + r2) * CCH + cc] = (_Float16)acc[mi][ni][r2];
        }
}

// ---------------- reduce: t7T[n][c2][k'] = (1/56) * sum_s part[s][n][k'][c2] ----------------
__global__ __launch_bounds__(256) void reduce_kernel(const _Float16* __restrict__ part,
                                                     _Float16* __restrict__ t7T) {
    __shared__ _Float16 tile[16][130];
    const int n  = blockIdx.y;
    const int k0 = blockIdx.x * 16;
    const int t  = threadIdx.x;
    const int c2 = t & 127;
    const int kh = t >> 7;
#pragma unroll
    for (int kk = 0; kk < 8; ++kk) {
        const int k = kh * 8 + kk;
        float sum = 0.f;
#pragma unroll
        for (int sp = 0; sp < SPLITK; ++sp)
            sum += (float)part[(((size_t)sp * NB + n) * K3C + k0 + k) * CCH + c2];
        tile[k][c2] = (_Float16)(sum * (1.0f / 56.0f));
    }
    __syncthreads();
    const int kt = t & 15;
    const int c0 = t >> 4;
#pragma unroll
    for (int cc = 0; cc < 8; ++cc) {
        const int cw = c0 * 8 + cc;
        t7T[((size_t)n * CCH + cw) * K3C + k0 + kt] = tile[kt][cw];
    }
}

// ---------------- GEMM2 (permuted K, coalesced staging, reg-prefetch, fused t8) ----------------
// out[n,c2,p] = t8tile*x + sc * sum_k' t7T[c2,k']*t3'[k',p]; t3'[j*128+c, p] = xT[p_shift(j)][c].
// Phase 0: t8tile[o][pl] = sum_c conv_w[o,c]*p5w[c]*xT[roll(pt0+pl)][c]  (As reused as scratch).
__global__ __launch_bounds__(256) void gemm2_kernel(const _Float16* __restrict__ xh,
                                                    const _Float16* __restrict__ xT,
                                                    const _Float16* __restrict__ t7T,
                                                    const float* __restrict__ conv_w,
                                                    const float* __restrict__ p5w,
                                                    float* __restrict__ out) {
    __shared__ _Float16 As[128 * 72];   // [c2][k_local]; phase 0: scratch [p_local][c] stride 136
    __shared__ _Float16 Bs[64 * 72];    // [p][k_local]
    __shared__ float t8tile[4 * 64];    // [o][p_local]
    __shared__ float wf[4 * 128];       // conv_w * p5w

    const int bid = blockIdx.x;
    const int r8  = bid & 7;
    const int g   = bid >> 3;
    const int n   = r8 + 8 * (g / 49);
    const int pt0 = (g % 49) * 64;
    const int tid = threadIdx.x;

    const int lrow = tid >> 3;          // 0..31
    const int lcol = (tid & 7) * 8;     // 0..56

    const _Float16* t7n = t7T + (size_t)n * CCH * K3C;
    const _Float16* xTn = xT + (size_t)n * HWP * CCH;

    // B row geometry (per s=0,1): prow = pt0 + s*32 + lrow
    int hbArr[2], wbArr[2];
#pragma unroll
    for (int sg = 0; sg < 2; ++sg) {
        const int prow = pt0 + sg * 32 + lrow;
        hbArr[sg] = prow / WWD;
        wbArr[sg] = prow - hbArr[sg] * WWD;
    }

    const int wave = tid >> 6;
    const int lane = tid & 63;
    const int l15  = lane & 15;
    const int quad = lane >> 4;
    const int wm   = (wave >> 1) * 64;
    const int wn   = (wave & 1) * 32;

    floatx4 acc[4][2];
#pragma unroll
    for (int a = 0; a < 4; ++a)
#pragma unroll
        for (int b = 0; b < 2; ++b) acc[a][b] = (floatx4){0.f,0.f,0.f,0.f};

    half8 av[4], bv[2];   // in-flight staging registers

    // ---- prologue: issue k0=0 loads EARLY so they overlap phase-0 compute ----
    {
#pragma unroll
        for (int sg = 0; sg < 4; ++sg)
            av[sg] = *(const half8*)(t7n + (size_t)(sg * 32 + lrow) * K3C + lcol);
#pragma unroll
        for (int sg = 0; sg < 2; ++sg) {
            const int wsrc = wbArr[sg] - 2;
            if (wsrc >= 0) {
                bv[sg] = *(const half8*)(xTn + ((size_t)hbArr[sg] * WWD + wsrc) * CCH + lcol);
            } else {
                half8 z; for (int i = 0; i < 8; ++i) z[i] = (_Float16)0.f; bv[sg] = z;
            }
        }
    }

    // ---- phase 0: compute t8tile (reuse As as [64][136] staging scratch) ----
    {
        wf[tid]       = conv_w[tid] * p5w[tid & 127];
        wf[tid + 256] = conv_w[tid + 256] * p5w[tid & 127];
        _Float16* tr = As;
        const int coff = (tid & 15) * 8;          // 0..120
#pragma unroll
        for (int q = 0; q < 4; ++q) {
            const int row = q * 16 + (tid >> 4);  // 0..63
            const int p   = pt0 + row;
            const int srcrow = (p >= WWD) ? (p - WWD) : (p + (HH - 1) * WWD);
            *(half8*)(&tr[row * 136 + coff]) = *(const half8*)(xTn + (size_t)srcrow * CCH + coff);
        }
        __syncthreads();
        const int o  = tid >> 6;                  // wave-uniform
        const int pl = tid & 63;
        const float* wrow = wf + o * 128;
        float a = 0.f;
#pragma unroll
        for (int cs = 0; cs < 16; ++cs) {
            const half8 v = *(const half8*)(&tr[pl * 136 + cs * 8]);
#pragma unroll
            for (int i = 0; i < 8; ++i) a += wrow[cs * 8 + i] * (float)v[i];
        }
        t8tile[o * 64 + pl] = a;
        __syncthreads();   // As free again; t8tile visible
    }

#pragma unroll
    for (int k0 = 0; k0 < K3C; k0 += 64) {
        // ---- commit staging regs to LDS ----
#pragma unroll
        for (int sg = 0; sg < 4; ++sg)
            *(half8*)(&As[(sg * 32 + lrow) * 72 + lcol]) = av[sg];
#pragma unroll
        for (int sg = 0; sg < 2; ++sg)
            *(half8*)(&Bs[(sg * 32 + lrow) * 72 + lcol]) = bv[sg];
        __syncthreads();
        // ---- issue next iteration's loads (overlap with MFMA) ----
        if (k0 + 64 < K3C) {
            const int kn  = k0 + 64;
            const int jn  = kn >> 7;
            const int c0k = kn & 127;
#pragma unroll
            for (int sg = 0; sg < 4; ++sg)
                av[sg] = *(const half8*)(t7n + (size_t)(sg * 32 + lrow) * K3C + kn + lcol);
#pragma unroll
            for (int sg = 0; sg < 2; ++sg) {
                const int wsrc = wbArr[sg] + 2 * jn - 2;
                if (wsrc >= 0 && wsrc < WWD) {
                    bv[sg] = *(const half8*)(xTn + ((size_t)hbArr[sg] * WWD + wsrc) * CCH + c0k + lcol);
                } else {
                    half8 z; for (int i = 0; i < 8; ++i) z[i] = (_Float16)0.f; bv[sg] = z;
                }
            }
        }
        // ---- MFMA ----
#pragma unroll
        for (int ks = 0; ks < 2; ++ks) {
            const int ko = ks * 32 + quad * 8;
            half8 af[4], bf[2];
#pragma unroll
            for (int mi = 0; mi < 4; ++mi) af[mi] = *(half8*)(&As[(wm + mi * 16 + l15) * 72 + ko]);
#pragma unroll
            for (int ni = 0; ni < 2; ++ni) bf[ni] = *(half8*)(&Bs[(wn + ni * 16 + l15) * 72 + ko]);
#pragma unroll
            for (int mi = 0; mi < 4; ++mi)
#pragma unroll
                for (int ni = 0; ni < 2; ++ni)
                    acc[mi][ni] = __builtin_amdgcn_mfma_f32_16x16x32_f16(af[mi], bf[ni], acc[mi][ni], 0, 0, 0);
        }
        __syncthreads();
    }

    const float sc = 0.05103103630798288f;  // 1/sqrt(384)
#pragma unroll
    for (int mi = 0; mi < 4; ++mi)
#pragma unroll
        for (int ni = 0; ni < 2; ++ni) {
            const int ccb = wm + mi * 16 + quad * 4;
            const int lp  = wn + ni * 16 + l15;     // p_local in [0,64)
            const int pp  = pt0 + lp;
#pragma unroll
            for (int r2 = 0; r2 < 4; ++r2) {
                const int c2 = ccb + r2;            // o = c2 & 3 == r2 (wave-uniform)
                const size_t oidx = ((size_t)n * CCH + c2) * HWP + pp;
                const float t9 = t8tile[r2 * 64 + lp] * (float)xh[oidx];
                out[oidx] = acc[mi][ni][r2] * sc + t9;
            }
        }
}

extern "C" void kernel_launch(void* const* d_in, const int* in_sizes, int n_in,
                              void* d_out, int out_size, void* d_ws, size_t ws_size,
                              hipStream_t stream) {
    const float* x      = (const float*)d_in[0];
    const float* p2w    = (const float*)d_in[1];
    const float* p5w    = (const float*)d_in[2];
    const float* conv_w = (const float*)d_in[3];
    float* out = (float*)d_out;

    // ws: xh 25.69MB | p2wh 2.41MB | (hole, ex-t8) | t7T 3.15MB | xT 25.69MB
    char* ws = (char*)d_ws;
    _Float16* xh   = (_Float16*)ws;
    _Float16* p2wh = (_Float16*)(ws + 25690112);
    _Float16* t7T  = (_Float16*)(ws + 25690112 + 2408448 + 1605632);
    _Float16* xT   = (_Float16*)(ws + 25690112 + 2408448 + 1605632 + 3145728);
    _Float16* part = (_Float16*)out;  // f16 partials (25.2MB) consumed by reduce before gemm2 writes out

    cvtp2w_kernel<<<dim3(K3C), dim3(256), 0, stream>>>(p2w, p2wh);
    cvt_xt_kernel<<<dim3(3136), dim3(256), 0, stream>>>(x, xh, xT);
    gemm1_kernel<<<dim3(768), dim3(256), 0, stream>>>(xh, p2wh, part);
    reduce_kernel<<<dim3(24, NB), dim3(256), 0, stream>>>(part, t7T);
    gemm2_kernel<<<dim3(1568), dim3(256), 0, stream>>>(xh, xT, t7T, conv_w, p5w, out);
}